// Round 12
// baseline (247.705 us; speedup 1.0000x reference)
//
#include <hip/hip_runtime.h>

#define N_NODES 50000
#define FH 16
#define NBUK 782          // 64-node buckets: bucket = dst >> 6
#define BSHIFT 6
#define BSTRIDE 800
#define TILE 4096
#define NCH2 64           // src-deg chunks
#define NRNG 8            // src-deg node ranges
#define RNGSZ 6250        // nodes per range (even)
#define NDCH 32           // dst-count chunks
#define C1CAP 4608        // passC1 max bucket size (u16 LDS)

// ---- ws layout (u32 words) ----
#define OFF_INVOUT   0u           // [3][N] f32
#define OFF_INVIN    150000u      // [3][N] f32
#define OFF_BSTART   302400u      // [3][800]
#define OFF_GCUR     304800u      // [3][800]
#define OFF_ROWPTR   307200u      // [3][N+1] u32 (absolute into srcSorted)
#define OFF_HPROJ    457216u      // [3][N][16] f32
#define OFF_AGGP     3657216u     // [3][N][16] f32 (scaled by invIn already)
#define OFF_SRCHIST  3657216u     // [3][64][25000] u32, ends 8457216 (alias: dead after k_prep,
                                  //  which completes BEFORE passB/passC1/relu_h2 writes)
#define OFF_BUKCNTP  8457216u     // [3][32][800] u32 = 76800, ends 8534016 (aliases pairs tail;
                                  //  dead after k_prep, pairs written later by k_passB_h1)
#define OFF_HS       6057216u     // [3][N] f32
#define OFF_PAIRS    6357216u     // Etot u32 packed (dst<<16 | src)
#define OFF_SRCSORT  10557216u    // Etot u16
// need = (OFF_SRCSORT + ceil(Etot/2)) * 4  ~= 50.6 MB

// K1: fused histograms. Blocks [0,1536): src-degree (chunk,range,rel).
// Blocks [1536,1632): dst bucket counts -> per-chunk partials (no atomics, no zeroing).
__global__ __launch_bounds__(256) void k_hist(
    const int* s0, const int* s1, const int* s2,
    const int* d0p, const int* d1p, const int* d2p,
    int E0, int E1, int E2,
    unsigned* __restrict__ histP, unsigned* __restrict__ bukCntP) {
    __shared__ unsigned bins[RNGSZ / 2];   // 3125 words; dst role uses first NBUK
    int bx = blockIdx.x;
    if (bx < NCH2 * NRNG * 3) {
        int c = bx % NCH2, rg = (bx / NCH2) % NRNG, r = bx / (NCH2 * NRNG);
        const int* arr = (r == 0) ? s0 : (r == 1) ? s1 : s2;
        int E = (r == 0) ? E0 : (r == 1) ? E1 : E2;
        for (int i = threadIdx.x; i < RNGSZ / 2; i += 256) bins[i] = 0u;
        __syncthreads();
        int lo = rg * RNGSZ;
        int per = (((E + NCH2 - 1) / NCH2) + 7) & ~7;
        int a0 = c * per, a1 = min(a0 + per, E);
        for (int i = a0 + (int)threadIdx.x * 8; i < a1; i += 2048) {
            if (i + 8 <= a1) {
                int4 v1 = *reinterpret_cast<const int4*>(arr + i);
                int4 v2 = *reinterpret_cast<const int4*>(arr + i + 4);
                unsigned d0 = (unsigned)(v1.x - lo), d1 = (unsigned)(v1.y - lo);
                unsigned d2 = (unsigned)(v1.z - lo), d3 = (unsigned)(v1.w - lo);
                unsigned d4 = (unsigned)(v2.x - lo), d5 = (unsigned)(v2.y - lo);
                unsigned d6 = (unsigned)(v2.z - lo), d7 = (unsigned)(v2.w - lo);
                if (d0 < (unsigned)RNGSZ) atomicAdd(&bins[d0 >> 1], (d0 & 1u) ? 65536u : 1u);
                if (d1 < (unsigned)RNGSZ) atomicAdd(&bins[d1 >> 1], (d1 & 1u) ? 65536u : 1u);
                if (d2 < (unsigned)RNGSZ) atomicAdd(&bins[d2 >> 1], (d2 & 1u) ? 65536u : 1u);
                if (d3 < (unsigned)RNGSZ) atomicAdd(&bins[d3 >> 1], (d3 & 1u) ? 65536u : 1u);
                if (d4 < (unsigned)RNGSZ) atomicAdd(&bins[d4 >> 1], (d4 & 1u) ? 65536u : 1u);
                if (d5 < (unsigned)RNGSZ) atomicAdd(&bins[d5 >> 1], (d5 & 1u) ? 65536u : 1u);
                if (d6 < (unsigned)RNGSZ) atomicAdd(&bins[d6 >> 1], (d6 & 1u) ? 65536u : 1u);
                if (d7 < (unsigned)RNGSZ) atomicAdd(&bins[d7 >> 1], (d7 & 1u) ? 65536u : 1u);
            } else {
                for (int k2 = i; k2 < a1; k2++) {
                    unsigned d = (unsigned)(arr[k2] - lo);
                    if (d < (unsigned)RNGSZ) atomicAdd(&bins[d >> 1], (d & 1u) ? 65536u : 1u);
                }
            }
        }
        __syncthreads();
        unsigned* out = histP + ((size_t)r * NCH2 + c) * 25000 + rg * (RNGSZ / 2);
        for (int i = threadIdx.x; i < RNGSZ / 2; i += 256) out[i] = bins[i];
        return;
    }
    int idx = bx - NCH2 * NRNG * 3;
    int c = idx % NDCH, r = idx / NDCH;
    const int* arr = (r == 0) ? d0p : (r == 1) ? d1p : d2p;
    int E = (r == 0) ? E0 : (r == 1) ? E1 : E2;
    for (int i = threadIdx.x; i < NBUK; i += 256) bins[i] = 0u;
    __syncthreads();
    int per = (((E + NDCH - 1) / NDCH) + 3) & ~3;
    int a0 = c * per, a1 = min(a0 + per, E);
    for (int i = a0 + (int)threadIdx.x * 4; i < a1; i += 1024) {
        if (i + 4 <= a1) {
            int4 v = *reinterpret_cast<const int4*>(arr + i);
            atomicAdd(&bins[((unsigned)v.x) >> BSHIFT], 1u);
            atomicAdd(&bins[((unsigned)v.y) >> BSHIFT], 1u);
            atomicAdd(&bins[((unsigned)v.z) >> BSHIFT], 1u);
            atomicAdd(&bins[((unsigned)v.w) >> BSHIFT], 1u);
        } else {
            for (int k2 = i; k2 < a1; k2++)
                atomicAdd(&bins[((unsigned)arr[k2]) >> BSHIFT], 1u);
        }
    }
    __syncthreads();
    unsigned* outp = bukCntP + ((size_t)r * NDCH + c) * BSTRIDE;
    for (int b = threadIdx.x; b < NBUK; b += 256) outp[b] = bins[b];
}

// K2: fused. Blocks x<196: src-hist reduce -> invOut. Block x==196: partial-sum + scan.
__global__ __launch_bounds__(256) void k_prep(const unsigned* __restrict__ histP,
                                              float* __restrict__ invOut,
                                              const unsigned* __restrict__ bukCntP,
                                              unsigned* __restrict__ bstart,
                                              unsigned* __restrict__ gcur) {
    int r = blockIdx.y;
    if (blockIdx.x < 196) {
        int n = blockIdx.x * 256 + threadIdx.x;
        if (n >= N_NODES) return;
        const unsigned* p = histP + (size_t)r * NCH2 * 25000 + (n >> 1);
        unsigned s = 0;
#pragma unroll
        for (int c = 0; c < NCH2; c++) {
            unsigned w = p[(size_t)c * 25000];
            s += (n & 1) ? (w >> 16) : (w & 0xFFFFu);
        }
        invOut[r * N_NODES + n] = rsqrtf((float)(s ? s : 1u));
        return;
    }
    __shared__ unsigned part[256];
    int t = threadIdx.x;
    unsigned loc[4]; unsigned s = 0;
#pragma unroll
    for (int k = 0; k < 4; k++) {
        int idx = 4 * t + k;
        unsigned v = 0;
        if (idx < NBUK) {
            const unsigned* p = bukCntP + (size_t)r * NDCH * BSTRIDE + idx;
            for (int c = 0; c < NDCH; c++) v += p[(size_t)c * BSTRIDE];
        }
        loc[k] = v; s += v;
    }
    part[t] = s;
    __syncthreads();
    for (int d = 1; d < 256; d <<= 1) {
        unsigned v = (t >= d) ? part[t - d] : 0u;
        __syncthreads();
        part[t] += v;
        __syncthreads();
    }
    unsigned run = part[t] - s;
#pragma unroll
    for (int k = 0; k < 4; k++) {
        int idx = 4 * t + k;
        if (idx <= NBUK) { bstart[r * BSTRIDE + idx] = run; gcur[r * BSTRIDE + idx] = run; }
        run += loc[k];
    }
}

// K3: fused. Blocks [0,768): passB bucket-scatter. Blocks [768,10143): h1 projection.
__global__ __launch_bounds__(256) void k_passB_h1(
    const int* s0p, const int* s1p, const int* s2p,
    const int* d0p, const int* d1p, const int* d2p,
    int E0, int E1, int E2, int po0, int po1, int po2,
    unsigned* __restrict__ pairsAll, unsigned* __restrict__ gcurAll,
    const float* __restrict__ x, const float* __restrict__ invOut,
    const float* __restrict__ W1, float* __restrict__ hproj) {
    __shared__ unsigned smem[NBUK * 3 + 256 + TILE * 2];   // 43.2 KB union
    int bx = blockIdx.x;
    if (bx >= 768) {
        // ---- h1 role ----
        float* sW = (float*)smem;            // 512
        float* sx = (float*)smem + 512;      // 512
        int idx = bx - 768;
        int r = idx / 3125;
        int n0 = (idx - r * 3125) * 16;
        const float* W = W1 + r * 32 * FH;
        int t = threadIdx.x;
        for (int i = t; i < 32 * FH; i += 256) sW[i] = W[i];
        for (int i = t; i < 16 * 32; i += 256) {
            int nn = i >> 5, kk = i & 31;
            int n = n0 + nn;
            sx[nn * 32 + kk] = (n < N_NODES) ? x[n * 32 + kk] : 0.0f;
        }
        __syncthreads();
        int nn = t >> 4, j = t & 15;
        int n = n0 + nn;
        if (n < N_NODES) {
            float s = 0.f;
#pragma unroll
            for (int k = 0; k < 32; k++) s += sx[nn * 32 + k] * sW[k * FH + j];
            hproj[((size_t)r * N_NODES + n) * FH + j] = s * invOut[r * N_NODES + n];
        }
        return;
    }
    // ---- passB role ----
    unsigned* cnt   = smem;
    unsigned* off   = smem + NBUK;
    unsigned* gbase = smem + 2 * NBUK;
    unsigned* part  = smem + 3 * NBUK;
    unsigned* spair = smem + 3 * NBUK + 256;
    unsigned* saddr = spair + TILE;
    int r = bx >> 8;
    int cidx = bx & 255;
    const int* src = (r == 0) ? s0p : (r == 1) ? s1p : s2p;
    const int* dst = (r == 0) ? d0p : (r == 1) ? d1p : d2p;
    int E = (r == 0) ? E0 : (r == 1) ? E1 : E2;
    unsigned* pairs = pairsAll + ((r == 0) ? po0 : (r == 1) ? po1 : po2);
    unsigned* gcur = gcurAll + r * BSTRIDE;
    int chunk = (((E + 255) / 256) + 15) & ~15;
    int c0 = cidx * chunk;
    int c1 = min(c0 + chunk, E);
    for (int t0 = c0; t0 < c1; t0 += TILE) {
        int tn = min(TILE, c1 - t0);
        for (int i = threadIdx.x; i < NBUK; i += 256) cnt[i] = 0u;
        __syncthreads();
        unsigned pk[16], bk[16], sl[16];
        if (tn == TILE) {
            int base = t0 + (int)threadIdx.x * 16;
#pragma unroll
            for (int q = 0; q < 4; q++) {
                int4 vs = *reinterpret_cast<const int4*>(src + base + q * 4);
                int4 vd = *reinterpret_cast<const int4*>(dst + base + q * 4);
                pk[q * 4 + 0] = ((unsigned)vd.x << 16) | (unsigned)vs.x;
                pk[q * 4 + 1] = ((unsigned)vd.y << 16) | (unsigned)vs.y;
                pk[q * 4 + 2] = ((unsigned)vd.z << 16) | (unsigned)vs.z;
                pk[q * 4 + 3] = ((unsigned)vd.w << 16) | (unsigned)vs.w;
                bk[q * 4 + 0] = (unsigned)vd.x >> BSHIFT;
                bk[q * 4 + 1] = (unsigned)vd.y >> BSHIFT;
                bk[q * 4 + 2] = (unsigned)vd.z >> BSHIFT;
                bk[q * 4 + 3] = (unsigned)vd.w >> BSHIFT;
            }
#pragma unroll
            for (int k = 0; k < 16; k++) sl[k] = atomicAdd(&cnt[bk[k]], 1u);
        } else {
#pragma unroll
            for (int k = 0; k < 16; k++) {
                int ii = k * 256 + (int)threadIdx.x;
                bk[k] = 0xFFFFFFFFu;
                if (ii < tn) {
                    int i = t0 + ii;
                    unsigned s = (unsigned)src[i], d = (unsigned)dst[i];
                    pk[k] = (d << 16) | s;
                    unsigned b = d >> BSHIFT;
                    bk[k] = b;
                    sl[k] = atomicAdd(&cnt[b], 1u);
                }
            }
        }
        __syncthreads();
        {
            int t = threadIdx.x;
            unsigned loc[4]; unsigned sloc = 0;
#pragma unroll
            for (int k2 = 0; k2 < 4; k2++) {
                int idx = 4 * t + k2;
                loc[k2] = (idx < NBUK) ? cnt[idx] : 0u;
                sloc += loc[k2];
            }
            part[t] = sloc;
            __syncthreads();
            for (int d = 1; d < 256; d <<= 1) {
                unsigned v = (t >= d) ? part[t - d] : 0u;
                __syncthreads();
                part[t] += v;
                __syncthreads();
            }
            unsigned run = part[t] - sloc;
#pragma unroll
            for (int k2 = 0; k2 < 4; k2++) {
                int idx = 4 * t + k2;
                if (idx < NBUK) off[idx] = run;
                run += loc[k2];
            }
        }
        __syncthreads();
        for (int b = threadIdx.x; b < NBUK; b += 256) {
            unsigned c = cnt[b];
            if (c) gbase[b] = atomicAdd(&gcur[b], c);
        }
        __syncthreads();
        if (tn == TILE) {
#pragma unroll
            for (int k = 0; k < 16; k++) {
                unsigned idx = off[bk[k]] + sl[k];
                spair[idx] = pk[k];
                saddr[idx] = gbase[bk[k]] + sl[k];
            }
        } else {
#pragma unroll
            for (int k = 0; k < 16; k++) {
                if (bk[k] != 0xFFFFFFFFu) {
                    unsigned idx = off[bk[k]] + sl[k];
                    spair[idx] = pk[k];
                    saddr[idx] = gbase[bk[k]] + sl[k];
                }
            }
        }
        __syncthreads();
#pragma unroll
        for (int k = 0; k < 16; k++) {
            int ii = k * 256 + (int)threadIdx.x;
            if (ii < tn) pairs[saddr[ii]] = spair[ii];
        }
        __syncthreads();
    }
}

// K4: layer-1 per-bucket (all 3 relations, z = relation):
// LDS counting sort by dst -> segmented float4 register accumulation.
__global__ __launch_bounds__(256) void k_passC1(
    const unsigned* __restrict__ pairsAll, int po1, int po2,
    const unsigned* __restrict__ bstartAll,
    const float4* __restrict__ h4All, float4* __restrict__ out4All,
    unsigned short* __restrict__ srcGAll, unsigned* __restrict__ rowptrAll,
    float* __restrict__ invInAll) {
    __shared__ unsigned cnt[64];
    __shared__ unsigned off[65];
    __shared__ unsigned cur[64];
    __shared__ unsigned short srcS[C1CAP];
    int b = blockIdx.x, t = threadIdx.x, r = blockIdx.z;
    int po = (r == 0) ? 0 : (r == 1) ? po1 : po2;
    const unsigned* pairs = pairsAll + po;
    const unsigned* bstart = bstartAll + r * BSTRIDE;
    const float4* h4 = h4All + (size_t)r * N_NODES * 4;
    float4* out4 = out4All + (size_t)r * N_NODES * 4;
    unsigned short* srcG = srcGAll + po;
    unsigned* rowptr = rowptrAll + (size_t)r * (N_NODES + 1);
    float* invIn = invInAll + (size_t)r * N_NODES;
    unsigned e0 = bstart[b], e1 = bstart[b + 1];
    if (e1 - e0 > (unsigned)C1CAP) e1 = e0 + (unsigned)C1CAP;
    int d0 = b << BSHIFT;
    if (t < 64) cnt[t] = 0u;
    __syncthreads();
    for (unsigned i = e0 + t; i < e1; i += 256)
        atomicAdd(&cnt[(pairs[i] >> 16) - (unsigned)d0], 1u);
    __syncthreads();
    if (t < 64) {
        unsigned cv = cnt[t];
        unsigned sc = cv;
#pragma unroll
        for (int d = 1; d < 64; d <<= 1) {
            unsigned v = __shfl_up(sc, d, 64);
            if (t >= d) sc += v;
        }
        off[t] = sc - cv;
        if (t == 63) off[64] = sc;
    }
    __syncthreads();
    if (t < 64) {
        cur[t] = off[t];
        int n = d0 + t;
        if (n < N_NODES) {
            rowptr[n] = (unsigned)po + e0 + off[t];
            unsigned dg = cnt[t];
            invIn[n] = rsqrtf((float)(dg ? dg : 1u));
        }
    }
    if (b == NBUK - 1 && t == 0) rowptr[N_NODES] = (unsigned)po + e1;
    __syncthreads();
    for (unsigned i = e0 + t; i < e1; i += 256) {
        unsigned p = pairs[i];
        unsigned d = (p >> 16) - (unsigned)d0;
        unsigned pos = atomicAdd(&cur[d], 1u);
        srcS[pos] = (unsigned short)(p & 0xFFFFu);
    }
    __syncthreads();
    {
        unsigned len = e1 - e0;
        for (unsigned i = t; i < len; i += 256) srcG[e0 + i] = srcS[i];
    }
    int unit = t >> 4, p = t & 15, k = p >> 2, fq = p & 3;
    for (int nd = unit; nd < 64; nd += 16) {
        unsigned o0 = off[nd], o1 = off[nd + 1];
        float ax = 0.f, ay = 0.f, az = 0.f, aw = 0.f;
        unsigned base = o0;
        for (; base + 8 <= o1; base += 8) {
            int s0 = srcS[base + k], s1 = srcS[base + 4 + k];
            float4 v0 = h4[(size_t)s0 * 4 + fq];
            float4 v1 = h4[(size_t)s1 * 4 + fq];
            ax += v0.x + v1.x; ay += v0.y + v1.y; az += v0.z + v1.z; aw += v0.w + v1.w;
        }
        for (; base < o1; base += 4) {
            unsigned idx = base + (unsigned)k;
            if (idx < o1) {
                int s = srcS[idx];
                float4 v = h4[(size_t)s * 4 + fq];
                ax += v.x; ay += v.y; az += v.z; aw += v.w;
            }
        }
        ax += __shfl_xor(ax, 4, 16); ay += __shfl_xor(ay, 4, 16);
        az += __shfl_xor(az, 4, 16); aw += __shfl_xor(aw, 4, 16);
        ax += __shfl_xor(ax, 8, 16); ay += __shfl_xor(ay, 8, 16);
        az += __shfl_xor(az, 8, 16); aw += __shfl_xor(aw, 8, 16);
        int n = d0 + nd;
        if (k == 0 && n < N_NODES) {
            unsigned dg = o1 - o0;
            float sc = rsqrtf((float)(dg ? dg : 1u));
            float4 res; res.x = ax * sc; res.y = ay * sc; res.z = az * sc; res.w = aw * sc;
            out4[(size_t)n * 4 + fq] = res;
        }
    }
}

// K5: hout = relu(sum_r aggP_r + sum_r b1_r) in registers -> hs[r] = dot(hout,W2[r])*invOut[r].
__global__ __launch_bounds__(256) void k_relu_h2(const float4* __restrict__ aggP4,
                                                 const float* __restrict__ invOut,
                                                 const float* __restrict__ b1,
                                                 const float* __restrict__ W2,
                                                 float* __restrict__ hs) {
    __shared__ float sW[3 * FH];
    __shared__ float sb[FH];
    int t = threadIdx.x;
    if (t < 48) sW[t] = W2[t];
    if (t < 16) sb[t] = b1[t] + b1[FH + t] + b1[2 * FH + t];
    __syncthreads();
    int n = blockIdx.x * 256 + t;
    if (n >= N_NODES) return;
    const size_t SL4 = (size_t)N_NODES * 4;
    float h[FH];
#pragma unroll
    for (int q = 0; q < 4; q++) {
        float4 a0 = aggP4[(size_t)n * 4 + q];
        float4 a1 = aggP4[SL4 + (size_t)n * 4 + q];
        float4 a2 = aggP4[2 * SL4 + (size_t)n * 4 + q];
        h[q * 4 + 0] = fmaxf(a0.x + a1.x + a2.x + sb[q * 4 + 0], 0.f);
        h[q * 4 + 1] = fmaxf(a0.y + a1.y + a2.y + sb[q * 4 + 1], 0.f);
        h[q * 4 + 2] = fmaxf(a0.z + a1.z + a2.z + sb[q * 4 + 2], 0.f);
        h[q * 4 + 3] = fmaxf(a0.w + a1.w + a2.w + sb[q * 4 + 3], 0.f);
    }
#pragma unroll
    for (int r = 0; r < 3; r++) {
        float s = 0.f;
#pragma unroll
        for (int j = 0; j < FH; j++) s += h[j] * sW[r * FH + j];
        hs[r * N_NODES + n] = s * invOut[r * N_NODES + n];
    }
}

// K6: fused layer-2 + final.
__global__ __launch_bounds__(256) void k_passC2f(
    const unsigned short* __restrict__ srcG, const unsigned* __restrict__ rowptr,
    const float* __restrict__ hsAll, const float* __restrict__ invIn,
    const float* __restrict__ b2, float* __restrict__ out) {
    int t = threadIdx.x;
    int unit = t >> 4, p = t & 15;
    int n = blockIdx.x * 16 + unit;
    if (n >= N_NODES) return;
    float tot = 0.f;
#pragma unroll
    for (int r = 0; r < 3; r++) {
        unsigned o0 = rowptr[r * (N_NODES + 1) + n];
        unsigned o1 = rowptr[r * (N_NODES + 1) + n + 1];
        const float* hs = hsAll + (size_t)r * N_NODES;
        float s = 0.f;
        for (unsigned i = o0 + (unsigned)p; i < o1; i += 16) s += hs[srcG[i]];
        tot += s * invIn[r * N_NODES + n];
    }
    tot += __shfl_xor(tot, 1, 16); tot += __shfl_xor(tot, 2, 16);
    tot += __shfl_xor(tot, 4, 16); tot += __shfl_xor(tot, 8, 16);
    if (p == 0) out[n] = tot + b2[0] + b2[1] + b2[2];
}

// =============== fallback (round-1) kernels ===============

__global__ void f_zero(float* __restrict__ p, int n) {
    int i = blockIdx.x * blockDim.x + threadIdx.x;
    if (i < n) p[i] = 0.0f;
}
__global__ void f_deg(const int* __restrict__ src, const int* __restrict__ dst, int E,
                      float* __restrict__ dout, float* __restrict__ din) {
    int i = blockIdx.x * blockDim.x + threadIdx.x;
    if (i < E) { atomicAdd(&dout[src[i]], 1.0f); atomicAdd(&din[dst[i]], 1.0f); }
}
__global__ void f_rsqrt(float* __restrict__ p, int n) {
    int i = blockIdx.x * blockDim.x + threadIdx.x;
    if (i < n) p[i] = rsqrtf(fmaxf(p[i], 1.0f));
}
__global__ void f_h1(const float* __restrict__ x, const float* __restrict__ invout,
                     const float* __restrict__ W, float* __restrict__ h) {
    __shared__ float sW[32 * FH];
    __shared__ float sx[16][32];
    int t = threadIdx.x;
    for (int i = t; i < 32 * FH; i += 256) sW[i] = W[i];
    int n0 = blockIdx.x * 16;
    for (int i = t; i < 16 * 32; i += 256) {
        int nn = i >> 5, kk = i & 31;
        int n = n0 + nn;
        sx[nn][kk] = (n < N_NODES) ? x[n * 32 + kk] : 0.0f;
    }
    __syncthreads();
    int nn = t >> 4, j = t & 15;
    int n = n0 + nn;
    if (n < N_NODES) {
        float s = 0.f;
#pragma unroll
        for (int k = 0; k < 32; k++) s += sx[nn][k] * sW[k * FH + j];
        h[n * FH + j] = s * invout[n];
    }
}
__global__ void f_agg1(const int* __restrict__ src, const int* __restrict__ dst, int E,
                       const float* __restrict__ h, const float* __restrict__ invin,
                       float* __restrict__ agg) {
    int idx = blockIdx.x * blockDim.x + threadIdx.x;
    if (idx < E * FH) {
        int e = idx >> 4, j = idx & 15;
        atomicAdd(&agg[dst[e] * FH + j], h[src[e] * FH + j] * invin[dst[e]]);
    }
}
__global__ void f_relu(float* __restrict__ agg, const float* __restrict__ b1) {
    int i = blockIdx.x * blockDim.x + threadIdx.x;
    if (i < N_NODES * FH) {
        int j = i & 15;
        agg[i] = fmaxf(agg[i] + b1[j] + b1[FH + j] + b1[2 * FH + j], 0.0f);
    }
}
__global__ void f_outinit(float* __restrict__ out, const float* __restrict__ b2) {
    int i = blockIdx.x * blockDim.x + threadIdx.x;
    if (i < N_NODES) out[i] = b2[0] + b2[1] + b2[2];
}
__global__ void f_h2(const float* __restrict__ h1, const float* __restrict__ invout,
                     const float* __restrict__ W2r, float* __restrict__ hsv) {
    int n = blockIdx.x * blockDim.x + threadIdx.x;
    if (n < N_NODES) {
        const float4* hp = (const float4*)(h1 + (size_t)n * FH);
        float s = 0.0f;
#pragma unroll
        for (int q = 0; q < 4; q++) {
            float4 hv = hp[q];
            s += hv.x * W2r[q * 4] + hv.y * W2r[q * 4 + 1] + hv.z * W2r[q * 4 + 2] + hv.w * W2r[q * 4 + 3];
        }
        hsv[n] = s * invout[n];
    }
}
__global__ void f_agg2(const int* __restrict__ src, const int* __restrict__ dst, int E,
                       const float* __restrict__ hsv, const float* __restrict__ invin,
                       float* __restrict__ out) {
    int e = blockIdx.x * blockDim.x + threadIdx.x;
    if (e < E) atomicAdd(&out[dst[e]], hsv[src[e]] * invin[dst[e]]);
}

// =============== host ===============

extern "C" void kernel_launch(void* const* d_in, const int* in_sizes, int n_in,
                              void* d_out, int out_size, void* d_ws, size_t ws_size,
                              hipStream_t stream) {
    const float* x = (const float*)d_in[0];
    const int* srcs[3] = { (const int*)d_in[1], (const int*)d_in[3], (const int*)d_in[5] };
    const int* dsts[3] = { (const int*)d_in[2], (const int*)d_in[4], (const int*)d_in[6] };
    int E[3] = { in_sizes[1], in_sizes[3], in_sizes[5] };
    const float* W1 = (const float*)d_in[7];
    const float* b1 = (const float*)d_in[8];
    const float* W2 = (const float*)d_in[9];
    const float* b2 = (const float*)d_in[10];
    float* out = (float*)d_out;
    const int N = N_NODES;
    const int B = 256;
    size_t Etot = (size_t)E[0] + E[1] + E[2];
    size_t need = ((size_t)OFF_SRCSORT + (Etot + 1) / 2) * 4u;

    if (ws_size >= need) {
        unsigned* ws = (unsigned*)d_ws;
        float* invOut = (float*)(ws + OFF_INVOUT);
        float* invIn  = (float*)(ws + OFF_INVIN);
        unsigned* bstart = ws + OFF_BSTART;
        unsigned* gcur   = ws + OFF_GCUR;
        unsigned* rowptr = ws + OFF_ROWPTR;
        float* hproj = (float*)(ws + OFF_HPROJ);
        float* aggP  = (float*)(ws + OFF_AGGP);
        unsigned* srcHist = ws + OFF_SRCHIST;
        unsigned* bukCntP = ws + OFF_BUKCNTP;
        float* hs    = (float*)(ws + OFF_HS);
        unsigned* pairs = ws + OFF_PAIRS;
        unsigned short* srcSort = (unsigned short*)(ws + OFF_SRCSORT);
        int po[3] = { 0, E[0], E[0] + E[1] };

        k_hist<<<NCH2 * NRNG * 3 + NDCH * 3, B, 0, stream>>>(
            srcs[0], srcs[1], srcs[2], dsts[0], dsts[1], dsts[2],
            E[0], E[1], E[2], srcHist, bukCntP);
        k_prep<<<dim3(197, 3), B, 0, stream>>>(srcHist, invOut, bukCntP, bstart, gcur);
        k_passB_h1<<<768 + 3 * 3125, B, 0, stream>>>(
            srcs[0], srcs[1], srcs[2], dsts[0], dsts[1], dsts[2],
            E[0], E[1], E[2], po[0], po[1], po[2], pairs, gcur,
            x, invOut, W1, hproj);
        k_passC1<<<dim3(NBUK, 1, 3), B, 0, stream>>>(
            pairs, po[1], po[2], bstart,
            (const float4*)hproj, (float4*)aggP,
            srcSort, rowptr, invIn);
        k_relu_h2<<<(N + B - 1) / B, B, 0, stream>>>((const float4*)aggP, invOut, b1, W2, hs);
        k_passC2f<<<(N + 15) / 16, B, 0, stream>>>(srcSort, rowptr, hs, invIn, b2, out);
    } else {
        // fallback: round-1 atomic path
        float* wsf = (float*)d_ws;
        float* invOut = wsf;
        float* invIn = wsf + 3 * (size_t)N;
        float* h = wsf + 6 * (size_t)N;
        float* agg = wsf + 22 * (size_t)N;
        float* hsv = wsf + 38 * (size_t)N;
        f_zero<<<(6 * N + B - 1) / B, B, 0, stream>>>(invOut, 6 * N);
        f_zero<<<(16 * N + B - 1) / B, B, 0, stream>>>(agg, 16 * N);
        for (int r = 0; r < 3; r++)
            f_deg<<<(E[r] + B - 1) / B, B, 0, stream>>>(srcs[r], dsts[r], E[r],
                                                        invOut + (size_t)r * N, invIn + (size_t)r * N);
        f_rsqrt<<<(6 * N + B - 1) / B, B, 0, stream>>>(invOut, 6 * N);
        for (int r = 0; r < 3; r++) {
            f_h1<<<(N + 15) / 16, B, 0, stream>>>(x, invOut + (size_t)r * N,
                                                  W1 + (size_t)r * 32 * FH, h);
            f_agg1<<<(E[r] * FH + B - 1) / B, B, 0, stream>>>(srcs[r], dsts[r], E[r], h,
                                                              invIn + (size_t)r * N, agg);
        }
        f_relu<<<(N * FH + B - 1) / B, B, 0, stream>>>(agg, b1);
        f_outinit<<<(N + B - 1) / B, B, 0, stream>>>(out, b2);
        for (int r = 0; r < 3; r++) {
            f_h2<<<(N + B - 1) / B, B, 0, stream>>>(agg, invOut + (size_t)r * N,
                                                    W2 + (size_t)r * FH, hsv);
            f_agg2<<<(E[r] + B - 1) / B, B, 0, stream>>>(srcs[r], dsts[r], E[r], hsv,
                                                         invIn + (size_t)r * N, out);
        }
    }
}

// Round 13
// 232.766 us; speedup vs baseline: 1.0642x; 1.0642x over previous
//
#include <hip/hip_runtime.h>

#define N_NODES 50000
#define FH 16
#define NBUK 782          // 64-node buckets: bucket = dst >> 6
#define BSHIFT 6
#define BSTRIDE 800
#define TILE 4096
#define NCH2 64           // src-deg chunks
#define NRNG 8            // src-deg node ranges
#define RNGSZ 6250        // nodes per range (even)
#define NDCH 256          // dst-count chunks (balanced with src role)
#define C1CAP 4608        // passC1 max bucket size (u16 LDS)

// ---- ws layout (u32 words) ----
#define OFF_INVOUT   0u           // [3][N] f32
#define OFF_INVIN    150000u      // [3][N] f32
#define OFF_BUKCNT   300000u      // [3][800] (memset to 0 each call)
#define OFF_BSTART   302400u      // [3][800]
#define OFF_GCUR     304800u      // [3][800]
#define OFF_ROWPTR   307200u      // [3][N+1] u32 (absolute into srcSorted)
#define OFF_HPROJ    457216u      // [3][N][16] f32
#define OFF_AGGP     3657216u     // [3][N][16] f32 (scaled by invIn already)
#define OFF_SRCHIST  3657216u     // [3][64][25000] u32, ends 8457216 (alias: dead after k_prep,
                                  //  which completes BEFORE passB/passC1/relu_h2 writes)
#define OFF_HS       6057216u     // [3][N] f32
#define OFF_PAIRS    6357216u     // Etot u32 packed (dst<<16 | src)
#define OFF_SRCSORT  10557216u    // Etot u16
// need = (OFF_SRCSORT + ceil(Etot/2)) * 4  ~= 50.6 MB

// K1: fused histograms, balanced roles.
// Blocks [0,1536): src-degree (chunk,range,rel) -> packed u16 partials.
// Blocks [1536,2304): dst bucket counts (NDCH=256 chunks/rel) -> global atomics on bukCnt.
__global__ __launch_bounds__(256) void k_hist(
    const int* s0, const int* s1, const int* s2,
    const int* d0p, const int* d1p, const int* d2p,
    int E0, int E1, int E2,
    unsigned* __restrict__ histP, unsigned* __restrict__ bukCnt) {
    __shared__ unsigned bins[RNGSZ / 2];   // 3125 words; dst role uses first NBUK
    int bx = blockIdx.x;
    if (bx < NCH2 * NRNG * 3) {
        int c = bx % NCH2, rg = (bx / NCH2) % NRNG, r = bx / (NCH2 * NRNG);
        const int* arr = (r == 0) ? s0 : (r == 1) ? s1 : s2;
        int E = (r == 0) ? E0 : (r == 1) ? E1 : E2;
        for (int i = threadIdx.x; i < RNGSZ / 2; i += 256) bins[i] = 0u;
        __syncthreads();
        int lo = rg * RNGSZ;
        int per = (((E + NCH2 - 1) / NCH2) + 7) & ~7;
        int a0 = c * per, a1 = min(a0 + per, E);
        for (int i = a0 + (int)threadIdx.x * 8; i < a1; i += 2048) {
            if (i + 8 <= a1) {
                int4 v1 = *reinterpret_cast<const int4*>(arr + i);
                int4 v2 = *reinterpret_cast<const int4*>(arr + i + 4);
                unsigned d0 = (unsigned)(v1.x - lo), d1 = (unsigned)(v1.y - lo);
                unsigned d2 = (unsigned)(v1.z - lo), d3 = (unsigned)(v1.w - lo);
                unsigned d4 = (unsigned)(v2.x - lo), d5 = (unsigned)(v2.y - lo);
                unsigned d6 = (unsigned)(v2.z - lo), d7 = (unsigned)(v2.w - lo);
                if (d0 < (unsigned)RNGSZ) atomicAdd(&bins[d0 >> 1], (d0 & 1u) ? 65536u : 1u);
                if (d1 < (unsigned)RNGSZ) atomicAdd(&bins[d1 >> 1], (d1 & 1u) ? 65536u : 1u);
                if (d2 < (unsigned)RNGSZ) atomicAdd(&bins[d2 >> 1], (d2 & 1u) ? 65536u : 1u);
                if (d3 < (unsigned)RNGSZ) atomicAdd(&bins[d3 >> 1], (d3 & 1u) ? 65536u : 1u);
                if (d4 < (unsigned)RNGSZ) atomicAdd(&bins[d4 >> 1], (d4 & 1u) ? 65536u : 1u);
                if (d5 < (unsigned)RNGSZ) atomicAdd(&bins[d5 >> 1], (d5 & 1u) ? 65536u : 1u);
                if (d6 < (unsigned)RNGSZ) atomicAdd(&bins[d6 >> 1], (d6 & 1u) ? 65536u : 1u);
                if (d7 < (unsigned)RNGSZ) atomicAdd(&bins[d7 >> 1], (d7 & 1u) ? 65536u : 1u);
            } else {
                for (int k2 = i; k2 < a1; k2++) {
                    unsigned d = (unsigned)(arr[k2] - lo);
                    if (d < (unsigned)RNGSZ) atomicAdd(&bins[d >> 1], (d & 1u) ? 65536u : 1u);
                }
            }
        }
        __syncthreads();
        unsigned* out = histP + ((size_t)r * NCH2 + c) * 25000 + rg * (RNGSZ / 2);
        for (int i = threadIdx.x; i < RNGSZ / 2; i += 256) out[i] = bins[i];
        return;
    }
    int idx = bx - NCH2 * NRNG * 3;
    int c = idx % NDCH, r = idx / NDCH;
    const int* arr = (r == 0) ? d0p : (r == 1) ? d1p : d2p;
    int E = (r == 0) ? E0 : (r == 1) ? E1 : E2;
    for (int i = threadIdx.x; i < NBUK; i += 256) bins[i] = 0u;
    __syncthreads();
    int per = (((E + NDCH - 1) / NDCH) + 3) & ~3;
    int a0 = c * per, a1 = min(a0 + per, E);
    for (int i = a0 + (int)threadIdx.x * 4; i < a1; i += 1024) {
        if (i + 4 <= a1) {
            int4 v = *reinterpret_cast<const int4*>(arr + i);
            atomicAdd(&bins[((unsigned)v.x) >> BSHIFT], 1u);
            atomicAdd(&bins[((unsigned)v.y) >> BSHIFT], 1u);
            atomicAdd(&bins[((unsigned)v.z) >> BSHIFT], 1u);
            atomicAdd(&bins[((unsigned)v.w) >> BSHIFT], 1u);
        } else {
            for (int k2 = i; k2 < a1; k2++)
                atomicAdd(&bins[((unsigned)arr[k2]) >> BSHIFT], 1u);
        }
    }
    __syncthreads();
    for (int b = threadIdx.x; b < NBUK; b += 256)
        if (bins[b]) atomicAdd(&bukCnt[r * BSTRIDE + b], bins[b]);
}

// K2: fused. Blocks x<196: src-hist reduce -> invOut. Block x==196: bucket scan.
__global__ __launch_bounds__(256) void k_prep(const unsigned* __restrict__ histP,
                                              float* __restrict__ invOut,
                                              const unsigned* __restrict__ bukCnt,
                                              unsigned* __restrict__ bstart,
                                              unsigned* __restrict__ gcur) {
    int r = blockIdx.y;
    if (blockIdx.x < 196) {
        int n = blockIdx.x * 256 + threadIdx.x;
        if (n >= N_NODES) return;
        const unsigned* p = histP + (size_t)r * NCH2 * 25000 + (n >> 1);
        unsigned s = 0;
#pragma unroll
        for (int c = 0; c < NCH2; c++) {
            unsigned w = p[(size_t)c * 25000];
            s += (n & 1) ? (w >> 16) : (w & 0xFFFFu);
        }
        invOut[r * N_NODES + n] = rsqrtf((float)(s ? s : 1u));
        return;
    }
    __shared__ unsigned part[256];
    int t = threadIdx.x;
    unsigned loc[4]; unsigned s = 0;
#pragma unroll
    for (int k = 0; k < 4; k++) {
        int idx = 4 * t + k;
        loc[k] = (idx < NBUK) ? bukCnt[r * BSTRIDE + idx] : 0u;
        s += loc[k];
    }
    part[t] = s;
    __syncthreads();
    for (int d = 1; d < 256; d <<= 1) {
        unsigned v = (t >= d) ? part[t - d] : 0u;
        __syncthreads();
        part[t] += v;
        __syncthreads();
    }
    unsigned run = part[t] - s;
#pragma unroll
    for (int k = 0; k < 4; k++) {
        int idx = 4 * t + k;
        if (idx <= NBUK) { bstart[r * BSTRIDE + idx] = run; gcur[r * BSTRIDE + idx] = run; }
        run += loc[k];
    }
}

// K3: bucket-scatter with in-LDS tile reorder. pair = (dst<<16)|src.
__global__ __launch_bounds__(256) void k_passB(
    const int* s0p, const int* s1p, const int* s2p,
    const int* d0p, const int* d1p, const int* d2p,
    int E0, int E1, int E2, int po0, int po1, int po2,
    unsigned* __restrict__ pairsAll, unsigned* __restrict__ gcurAll) {
    __shared__ unsigned cnt[NBUK];
    __shared__ unsigned off[NBUK];
    __shared__ unsigned gbase[NBUK];
    __shared__ unsigned part[256];
    __shared__ unsigned spair[TILE];
    __shared__ unsigned saddr[TILE];
    int r = blockIdx.z;
    const int* src = (r == 0) ? s0p : (r == 1) ? s1p : s2p;
    const int* dst = (r == 0) ? d0p : (r == 1) ? d1p : d2p;
    int E = (r == 0) ? E0 : (r == 1) ? E1 : E2;
    unsigned* pairs = pairsAll + ((r == 0) ? po0 : (r == 1) ? po1 : po2);
    unsigned* gcur = gcurAll + r * BSTRIDE;
    int nb = gridDim.x;
    int chunk = (((E + nb - 1) / nb) + 15) & ~15;
    int c0 = blockIdx.x * chunk;
    int c1 = min(c0 + chunk, E);
    for (int t0 = c0; t0 < c1; t0 += TILE) {
        int tn = min(TILE, c1 - t0);
        for (int i = threadIdx.x; i < NBUK; i += 256) cnt[i] = 0u;
        __syncthreads();
        unsigned pk[16], bk[16], sl[16];
        if (tn == TILE) {
            int base = t0 + (int)threadIdx.x * 16;
#pragma unroll
            for (int q = 0; q < 4; q++) {
                int4 vs = *reinterpret_cast<const int4*>(src + base + q * 4);
                int4 vd = *reinterpret_cast<const int4*>(dst + base + q * 4);
                pk[q * 4 + 0] = ((unsigned)vd.x << 16) | (unsigned)vs.x;
                pk[q * 4 + 1] = ((unsigned)vd.y << 16) | (unsigned)vs.y;
                pk[q * 4 + 2] = ((unsigned)vd.z << 16) | (unsigned)vs.z;
                pk[q * 4 + 3] = ((unsigned)vd.w << 16) | (unsigned)vs.w;
                bk[q * 4 + 0] = (unsigned)vd.x >> BSHIFT;
                bk[q * 4 + 1] = (unsigned)vd.y >> BSHIFT;
                bk[q * 4 + 2] = (unsigned)vd.z >> BSHIFT;
                bk[q * 4 + 3] = (unsigned)vd.w >> BSHIFT;
            }
#pragma unroll
            for (int k = 0; k < 16; k++) sl[k] = atomicAdd(&cnt[bk[k]], 1u);
        } else {
#pragma unroll
            for (int k = 0; k < 16; k++) {
                int ii = k * 256 + (int)threadIdx.x;
                bk[k] = 0xFFFFFFFFu;
                if (ii < tn) {
                    int i = t0 + ii;
                    unsigned s = (unsigned)src[i], d = (unsigned)dst[i];
                    pk[k] = (d << 16) | s;
                    unsigned b = d >> BSHIFT;
                    bk[k] = b;
                    sl[k] = atomicAdd(&cnt[b], 1u);
                }
            }
        }
        __syncthreads();
        {
            int t = threadIdx.x;
            unsigned loc[4]; unsigned sloc = 0;
#pragma unroll
            for (int k2 = 0; k2 < 4; k2++) {
                int idx = 4 * t + k2;
                loc[k2] = (idx < NBUK) ? cnt[idx] : 0u;
                sloc += loc[k2];
            }
            part[t] = sloc;
            __syncthreads();
            for (int d = 1; d < 256; d <<= 1) {
                unsigned v = (t >= d) ? part[t - d] : 0u;
                __syncthreads();
                part[t] += v;
                __syncthreads();
            }
            unsigned run = part[t] - sloc;
#pragma unroll
            for (int k2 = 0; k2 < 4; k2++) {
                int idx = 4 * t + k2;
                if (idx < NBUK) off[idx] = run;
                run += loc[k2];
            }
        }
        __syncthreads();
        for (int b = threadIdx.x; b < NBUK; b += 256) {
            unsigned c = cnt[b];
            if (c) gbase[b] = atomicAdd(&gcur[b], c);
        }
        __syncthreads();
        if (tn == TILE) {
#pragma unroll
            for (int k = 0; k < 16; k++) {
                unsigned idx = off[bk[k]] + sl[k];
                spair[idx] = pk[k];
                saddr[idx] = gbase[bk[k]] + sl[k];
            }
        } else {
#pragma unroll
            for (int k = 0; k < 16; k++) {
                if (bk[k] != 0xFFFFFFFFu) {
                    unsigned idx = off[bk[k]] + sl[k];
                    spair[idx] = pk[k];
                    saddr[idx] = gbase[bk[k]] + sl[k];
                }
            }
        }
        __syncthreads();
#pragma unroll
        for (int k = 0; k < 16; k++) {
            int ii = k * 256 + (int)threadIdx.x;
            if (ii < tn) pairs[saddr[ii]] = spair[ii];
        }
        __syncthreads();
    }
}

// K4: h_r[n][j] = (x[n,:] . W1[r][:,j]) * invOut_r[n]   (own kernel, 4.2 KB LDS)
__global__ __launch_bounds__(256) void k_h1(const float* __restrict__ x, const float* __restrict__ invOut,
                                            const float* __restrict__ W1, float* __restrict__ hproj) {
    __shared__ float sW[32 * FH];
    __shared__ float sx[16][32];
    int r = blockIdx.y;
    const float* W = W1 + r * 32 * FH;
    int t = threadIdx.x;
    for (int i = t; i < 32 * FH; i += 256) sW[i] = W[i];
    int n0 = blockIdx.x * 16;
    for (int i = t; i < 16 * 32; i += 256) {
        int nn = i >> 5, kk = i & 31;
        int n = n0 + nn;
        sx[nn][kk] = (n < N_NODES) ? x[n * 32 + kk] : 0.0f;
    }
    __syncthreads();
    int nn = t >> 4, j = t & 15;
    int n = n0 + nn;
    if (n < N_NODES) {
        float s = 0.f;
#pragma unroll
        for (int k = 0; k < 32; k++) s += sx[nn][k] * sW[k * FH + j];
        hproj[((size_t)r * N_NODES + n) * FH + j] = s * invOut[r * N_NODES + n];
    }
}

// K5: layer-1 per-bucket (all 3 relations, z = relation):
// LDS counting sort by dst -> segmented float4 register accumulation.
__global__ __launch_bounds__(256) void k_passC1(
    const unsigned* __restrict__ pairsAll, int po1, int po2,
    const unsigned* __restrict__ bstartAll,
    const float4* __restrict__ h4All, float4* __restrict__ out4All,
    unsigned short* __restrict__ srcGAll, unsigned* __restrict__ rowptrAll,
    float* __restrict__ invInAll) {
    __shared__ unsigned cnt[64];
    __shared__ unsigned off[65];
    __shared__ unsigned cur[64];
    __shared__ unsigned short srcS[C1CAP];
    int b = blockIdx.x, t = threadIdx.x, r = blockIdx.z;
    int po = (r == 0) ? 0 : (r == 1) ? po1 : po2;
    const unsigned* pairs = pairsAll + po;
    const unsigned* bstart = bstartAll + r * BSTRIDE;
    const float4* h4 = h4All + (size_t)r * N_NODES * 4;
    float4* out4 = out4All + (size_t)r * N_NODES * 4;
    unsigned short* srcG = srcGAll + po;
    unsigned* rowptr = rowptrAll + (size_t)r * (N_NODES + 1);
    float* invIn = invInAll + (size_t)r * N_NODES;
    unsigned e0 = bstart[b], e1 = bstart[b + 1];
    if (e1 - e0 > (unsigned)C1CAP) e1 = e0 + (unsigned)C1CAP;
    int d0 = b << BSHIFT;
    if (t < 64) cnt[t] = 0u;
    __syncthreads();
    for (unsigned i = e0 + t; i < e1; i += 256)
        atomicAdd(&cnt[(pairs[i] >> 16) - (unsigned)d0], 1u);
    __syncthreads();
    if (t < 64) {
        unsigned cv = cnt[t];
        unsigned sc = cv;
#pragma unroll
        for (int d = 1; d < 64; d <<= 1) {
            unsigned v = __shfl_up(sc, d, 64);
            if (t >= d) sc += v;
        }
        off[t] = sc - cv;
        if (t == 63) off[64] = sc;
    }
    __syncthreads();
    if (t < 64) {
        cur[t] = off[t];
        int n = d0 + t;
        if (n < N_NODES) {
            rowptr[n] = (unsigned)po + e0 + off[t];
            unsigned dg = cnt[t];
            invIn[n] = rsqrtf((float)(dg ? dg : 1u));
        }
    }
    if (b == NBUK - 1 && t == 0) rowptr[N_NODES] = (unsigned)po + e1;
    __syncthreads();
    for (unsigned i = e0 + t; i < e1; i += 256) {
        unsigned p = pairs[i];
        unsigned d = (p >> 16) - (unsigned)d0;
        unsigned pos = atomicAdd(&cur[d], 1u);
        srcS[pos] = (unsigned short)(p & 0xFFFFu);
    }
    __syncthreads();
    {
        unsigned len = e1 - e0;
        for (unsigned i = t; i < len; i += 256) srcG[e0 + i] = srcS[i];
    }
    int unit = t >> 4, p = t & 15, k = p >> 2, fq = p & 3;
    for (int nd = unit; nd < 64; nd += 16) {
        unsigned o0 = off[nd], o1 = off[nd + 1];
        float ax = 0.f, ay = 0.f, az = 0.f, aw = 0.f;
        unsigned base = o0;
        for (; base + 8 <= o1; base += 8) {
            int s0 = srcS[base + k], s1 = srcS[base + 4 + k];
            float4 v0 = h4[(size_t)s0 * 4 + fq];
            float4 v1 = h4[(size_t)s1 * 4 + fq];
            ax += v0.x + v1.x; ay += v0.y + v1.y; az += v0.z + v1.z; aw += v0.w + v1.w;
        }
        for (; base < o1; base += 4) {
            unsigned idx = base + (unsigned)k;
            if (idx < o1) {
                int s = srcS[idx];
                float4 v = h4[(size_t)s * 4 + fq];
                ax += v.x; ay += v.y; az += v.z; aw += v.w;
            }
        }
        ax += __shfl_xor(ax, 4, 16); ay += __shfl_xor(ay, 4, 16);
        az += __shfl_xor(az, 4, 16); aw += __shfl_xor(aw, 4, 16);
        ax += __shfl_xor(ax, 8, 16); ay += __shfl_xor(ay, 8, 16);
        az += __shfl_xor(az, 8, 16); aw += __shfl_xor(aw, 8, 16);
        int n = d0 + nd;
        if (k == 0 && n < N_NODES) {
            unsigned dg = o1 - o0;
            float sc = rsqrtf((float)(dg ? dg : 1u));
            float4 res; res.x = ax * sc; res.y = ay * sc; res.z = az * sc; res.w = aw * sc;
            out4[(size_t)n * 4 + fq] = res;
        }
    }
}

// K6: hout = relu(sum_r aggP_r + sum_r b1_r) in registers -> hs[r] = dot(hout,W2[r])*invOut[r].
__global__ __launch_bounds__(256) void k_relu_h2(const float4* __restrict__ aggP4,
                                                 const float* __restrict__ invOut,
                                                 const float* __restrict__ b1,
                                                 const float* __restrict__ W2,
                                                 float* __restrict__ hs) {
    __shared__ float sW[3 * FH];
    __shared__ float sb[FH];
    int t = threadIdx.x;
    if (t < 48) sW[t] = W2[t];
    if (t < 16) sb[t] = b1[t] + b1[FH + t] + b1[2 * FH + t];
    __syncthreads();
    int n = blockIdx.x * 256 + t;
    if (n >= N_NODES) return;
    const size_t SL4 = (size_t)N_NODES * 4;
    float h[FH];
#pragma unroll
    for (int q = 0; q < 4; q++) {
        float4 a0 = aggP4[(size_t)n * 4 + q];
        float4 a1 = aggP4[SL4 + (size_t)n * 4 + q];
        float4 a2 = aggP4[2 * SL4 + (size_t)n * 4 + q];
        h[q * 4 + 0] = fmaxf(a0.x + a1.x + a2.x + sb[q * 4 + 0], 0.f);
        h[q * 4 + 1] = fmaxf(a0.y + a1.y + a2.y + sb[q * 4 + 1], 0.f);
        h[q * 4 + 2] = fmaxf(a0.z + a1.z + a2.z + sb[q * 4 + 2], 0.f);
        h[q * 4 + 3] = fmaxf(a0.w + a1.w + a2.w + sb[q * 4 + 3], 0.f);
    }
#pragma unroll
    for (int r = 0; r < 3; r++) {
        float s = 0.f;
#pragma unroll
        for (int j = 0; j < FH; j++) s += h[j] * sW[r * FH + j];
        hs[r * N_NODES + n] = s * invOut[r * N_NODES + n];
    }
}

// K7: fused layer-2 + final.
__global__ __launch_bounds__(256) void k_passC2f(
    const unsigned short* __restrict__ srcG, const unsigned* __restrict__ rowptr,
    const float* __restrict__ hsAll, const float* __restrict__ invIn,
    const float* __restrict__ b2, float* __restrict__ out) {
    int t = threadIdx.x;
    int unit = t >> 4, p = t & 15;
    int n = blockIdx.x * 16 + unit;
    if (n >= N_NODES) return;
    float tot = 0.f;
#pragma unroll
    for (int r = 0; r < 3; r++) {
        unsigned o0 = rowptr[r * (N_NODES + 1) + n];
        unsigned o1 = rowptr[r * (N_NODES + 1) + n + 1];
        const float* hs = hsAll + (size_t)r * N_NODES;
        float s = 0.f;
        for (unsigned i = o0 + (unsigned)p; i < o1; i += 16) s += hs[srcG[i]];
        tot += s * invIn[r * N_NODES + n];
    }
    tot += __shfl_xor(tot, 1, 16); tot += __shfl_xor(tot, 2, 16);
    tot += __shfl_xor(tot, 4, 16); tot += __shfl_xor(tot, 8, 16);
    if (p == 0) out[n] = tot + b2[0] + b2[1] + b2[2];
}

// =============== fallback (round-1) kernels ===============

__global__ void f_zero(float* __restrict__ p, int n) {
    int i = blockIdx.x * blockDim.x + threadIdx.x;
    if (i < n) p[i] = 0.0f;
}
__global__ void f_deg(const int* __restrict__ src, const int* __restrict__ dst, int E,
                      float* __restrict__ dout, float* __restrict__ din) {
    int i = blockIdx.x * blockDim.x + threadIdx.x;
    if (i < E) { atomicAdd(&dout[src[i]], 1.0f); atomicAdd(&din[dst[i]], 1.0f); }
}
__global__ void f_rsqrt(float* __restrict__ p, int n) {
    int i = blockIdx.x * blockDim.x + threadIdx.x;
    if (i < n) p[i] = rsqrtf(fmaxf(p[i], 1.0f));
}
__global__ void f_agg1(const int* __restrict__ src, const int* __restrict__ dst, int E,
                       const float* __restrict__ h, const float* __restrict__ invin,
                       float* __restrict__ agg) {
    int idx = blockIdx.x * blockDim.x + threadIdx.x;
    if (idx < E * FH) {
        int e = idx >> 4, j = idx & 15;
        atomicAdd(&agg[dst[e] * FH + j], h[src[e] * FH + j] * invin[dst[e]]);
    }
}
__global__ void f_relu(float* __restrict__ agg, const float* __restrict__ b1) {
    int i = blockIdx.x * blockDim.x + threadIdx.x;
    if (i < N_NODES * FH) {
        int j = i & 15;
        agg[i] = fmaxf(agg[i] + b1[j] + b1[FH + j] + b1[2 * FH + j], 0.0f);
    }
}
__global__ void f_outinit(float* __restrict__ out, const float* __restrict__ b2) {
    int i = blockIdx.x * blockDim.x + threadIdx.x;
    if (i < N_NODES) out[i] = b2[0] + b2[1] + b2[2];
}
__global__ void f_h2(const float* __restrict__ h1, const float* __restrict__ invout,
                     const float* __restrict__ W2r, float* __restrict__ hsv) {
    int n = blockIdx.x * blockDim.x + threadIdx.x;
    if (n < N_NODES) {
        const float4* hp = (const float4*)(h1 + (size_t)n * FH);
        float s = 0.0f;
#pragma unroll
        for (int q = 0; q < 4; q++) {
            float4 hv = hp[q];
            s += hv.x * W2r[q * 4] + hv.y * W2r[q * 4 + 1] + hv.z * W2r[q * 4 + 2] + hv.w * W2r[q * 4 + 3];
        }
        hsv[n] = s * invout[n];
    }
}
__global__ void f_agg2(const int* __restrict__ src, const int* __restrict__ dst, int E,
                       const float* __restrict__ hsv, const float* __restrict__ invin,
                       float* __restrict__ out) {
    int e = blockIdx.x * blockDim.x + threadIdx.x;
    if (e < E) atomicAdd(&out[dst[e]], hsv[src[e]] * invin[dst[e]]);
}

// =============== host ===============

extern "C" void kernel_launch(void* const* d_in, const int* in_sizes, int n_in,
                              void* d_out, int out_size, void* d_ws, size_t ws_size,
                              hipStream_t stream) {
    const float* x = (const float*)d_in[0];
    const int* srcs[3] = { (const int*)d_in[1], (const int*)d_in[3], (const int*)d_in[5] };
    const int* dsts[3] = { (const int*)d_in[2], (const int*)d_in[4], (const int*)d_in[6] };
    int E[3] = { in_sizes[1], in_sizes[3], in_sizes[5] };
    const float* W1 = (const float*)d_in[7];
    const float* b1 = (const float*)d_in[8];
    const float* W2 = (const float*)d_in[9];
    const float* b2 = (const float*)d_in[10];
    float* out = (float*)d_out;
    const int N = N_NODES;
    const int B = 256;
    size_t Etot = (size_t)E[0] + E[1] + E[2];
    size_t need = ((size_t)OFF_SRCSORT + (Etot + 1) / 2) * 4u;

    if (ws_size >= need) {
        unsigned* ws = (unsigned*)d_ws;
        float* invOut = (float*)(ws + OFF_INVOUT);
        float* invIn  = (float*)(ws + OFF_INVIN);
        unsigned* bukCnt = ws + OFF_BUKCNT;
        unsigned* bstart = ws + OFF_BSTART;
        unsigned* gcur   = ws + OFF_GCUR;
        unsigned* rowptr = ws + OFF_ROWPTR;
        float* hproj = (float*)(ws + OFF_HPROJ);
        float* aggP  = (float*)(ws + OFF_AGGP);
        unsigned* srcHist = ws + OFF_SRCHIST;
        float* hs    = (float*)(ws + OFF_HS);
        unsigned* pairs = ws + OFF_PAIRS;
        unsigned short* srcSort = (unsigned short*)(ws + OFF_SRCSORT);
        int po[3] = { 0, E[0], E[0] + E[1] };

        hipMemsetAsync(bukCnt, 0, 3 * BSTRIDE * 4, stream);
        k_hist<<<NCH2 * NRNG * 3 + NDCH * 3, B, 0, stream>>>(
            srcs[0], srcs[1], srcs[2], dsts[0], dsts[1], dsts[2],
            E[0], E[1], E[2], srcHist, bukCnt);
        k_prep<<<dim3(197, 3), B, 0, stream>>>(srcHist, invOut, bukCnt, bstart, gcur);
        k_passB<<<dim3(256, 1, 3), B, 0, stream>>>(
            srcs[0], srcs[1], srcs[2], dsts[0], dsts[1], dsts[2],
            E[0], E[1], E[2], po[0], po[1], po[2], pairs, gcur);
        k_h1<<<dim3((N + 15) / 16, 3), B, 0, stream>>>(x, invOut, W1, hproj);
        k_passC1<<<dim3(NBUK, 1, 3), B, 0, stream>>>(
            pairs, po[1], po[2], bstart,
            (const float4*)hproj, (float4*)aggP,
            srcSort, rowptr, invIn);
        k_relu_h2<<<(N + B - 1) / B, B, 0, stream>>>((const float4*)aggP, invOut, b1, W2, hs);
        k_passC2f<<<(N + 15) / 16, B, 0, stream>>>(srcSort, rowptr, hs, invIn, b2, out);
    } else {
        // fallback: round-1 atomic path
        float* wsf = (float*)d_ws;
        float* invOut = wsf;
        float* invIn = wsf + 3 * (size_t)N;
        float* h = wsf + 6 * (size_t)N;
        float* agg = wsf + 22 * (size_t)N;
        float* hsv = wsf + 38 * (size_t)N;
        f_zero<<<(6 * N + B - 1) / B, B, 0, stream>>>(invOut, 6 * N);
        f_zero<<<(16 * N + B - 1) / B, B, 0, stream>>>(agg, 16 * N);
        for (int r = 0; r < 3; r++)
            f_deg<<<(E[r] + B - 1) / B, B, 0, stream>>>(srcs[r], dsts[r], E[r],
                                                        invOut + (size_t)r * N, invIn + (size_t)r * N);
        f_rsqrt<<<(6 * N + B - 1) / B, B, 0, stream>>>(invOut, 6 * N);
        for (int r = 0; r < 3; r++) {
            k_h1<<<dim3((N + 15) / 16, 1), B, 0, stream>>>(x, invOut + (size_t)r * N,
                                                           W1 + (size_t)r * 32 * FH, h);
            f_agg1<<<(E[r] * FH + B - 1) / B, B, 0, stream>>>(srcs[r], dsts[r], E[r], h,
                                                              invIn + (size_t)r * N, agg);
        }
        f_relu<<<(N * FH + B - 1) / B, B, 0, stream>>>(agg, b1);
        f_outinit<<<(N + B - 1) / B, B, 0, stream>>>(out, b2);
        for (int r = 0; r < 3; r++) {
            f_h2<<<(N + B - 1) / B, B, 0, stream>>>(agg, invOut + (size_t)r * N,
                                                    W2 + (size_t)r * FH, hsv);
            f_agg2<<<(E[r] + B - 1) / B, B, 0, stream>>>(srcs[r], dsts[r], E[r], hsv,
                                                         invIn + (size_t)r * N, out);
        }
    }
}